// Round 10
// baseline (62.456 us; speedup 1.0000x reference)
//
#include <hip/hip_runtime.h>
#include <hip/hip_fp16.h>

#define OUT_H 7
#define OUT_W 7
#define NPOS  49
#define RATIO 2
#define SCALE 0.25f
#define CCH 256
#define FH 200
#define FW 200
#define FHW (FH * FW)          // 40000
#define LROW 65                // ODD row stride (floats): bank stride 1 -> conflict-free

struct __align__(16) H8 { __half2 h[4]; };   // 8 fp16 channels

__device__ __forceinline__ void acc8(float (&a)[8], const H8& v, float w) {
    #pragma unroll
    for (int k = 0; k < 4; ++k) {
        a[2*k]   = fmaf(__low2float(v.h[k]),  w, a[2*k]);
        a[2*k+1] = fmaf(__high2float(v.h[k]), w, a[2*k+1]);
    }
}

// ---------------- Transpose: (B, 256, 40000) fp32 -> (B, 40000, 256) fp16 ---
// Proven ~15 us (HBM/L3-bound). Do not touch.
__global__ __launch_bounds__(256) void transpose_cp(
    const float* __restrict__ in, __half* __restrict__ outT)
{
    int bid = blockIdx.x;               // grid = B * 4 * 625
    int pt   = bid % 625;               // pixel tile (64 pixels)
    int rest = bid / 625;
    int ct   = rest & 3;                // channel tile (64 ch)
    int b    = rest >> 2;

    __shared__ unsigned short tile[64][66];   // [pix][c]
    int tid = threadIdx.x;
    int pix0 = pt * 64, c0 = ct * 64;
    int xl = tid & 63;

    const float* src = in + ((size_t)b * CCH + c0) * FHW + pix0;
    #pragma unroll
    for (int k = 0; k < 16; ++k) {
        int cl = (tid >> 6) + 4 * k;    // 0..63
        tile[xl][cl] = __half_as_ushort(__float2half(src[(size_t)cl * FHW + xl]));
    }
    __syncthreads();

    __half* dst = outT + ((size_t)b * FHW + pix0) * CCH + c0;
    #pragma unroll
    for (int j = 0; j < 8; ++j) {
        int idx = tid + 256 * j;        // 0..2047
        int pl = idx >> 5;              // 0..63
        int cp = idx & 31;              // half2 index: c = 2*cp
        *(unsigned int*)((char*)dst + (size_t)pl * (CCH * 2) + 4 * cp) =
            *(const unsigned int*)&tile[pl][2 * cp];
    }
}

// ---------------- ROI Align gather v8: forced 16-deep load batch ------------
// grid = 4N: block (n = bid>>2, cq = bid&3) owns 64 channels of ROI n.
// Lane = (g = position group, l = 8-channel group). Per position: compute all
// corner addrs/weights, issue ALL 16 H8 loads, then a memory-clobber asm
// barrier (loads cannot sink past it -> 16 outstanding VMEM per thread),
// then 128 FMAs. launch_bounds(256,3): VGPR cap ~170, 12 waves/CU.
// LDS: LROW=65 (odd) + scalar b32 writes/reads -> zero bank conflicts.
__global__ __launch_bounds__(256, 3) void roi_gather_v8(
    const __half* __restrict__ featT,  // (B, 40000, 256) fp16
    const float* __restrict__ rois,    // (N, 5)
    float* __restrict__ out,           // (N, 256, 7, 7)
    int N)
{
    int bid = blockIdx.x;
    int n  = bid >> 2;
    int cq = bid & 3;
    int tid = threadIdx.x;
    int wave = tid >> 6, lane = tid & 63;
    int g = lane >> 3;                  // position group 0..7
    int l = lane & 7;                   // channel group (8 ch)

    __shared__ float lds[NPOS * LROW];

    const float* r = rois + (size_t)n * 5;
    int   b  = (int)r[0];
    float x1 = r[1] * SCALE, y1 = r[2] * SCALE;
    float roi_w = fmaxf(r[3] * SCALE - x1, 1.0f);
    float roi_h = fmaxf(r[4] * SCALE - y1, 1.0f);
    float step_x = roi_w * (1.0f / (OUT_W * RATIO));
    float step_y = roi_h * (1.0f / (OUT_H * RATIO));

    const char* base = (const char*)featT + (size_t)b * ((size_t)FHW * CCH * 2);
    const uint32_t laneoff = (uint32_t)(cq * 64 + l * 8) * 2;

    #pragma unroll 1
    for (int rnd = 0; rnd < 2; ++rnd) {
        int p = rnd * 32 + wave * 8 + g;    // 0..63
        if (p < NPOS) {
            int ph = p / OUT_W;
            int pw = p - ph * OUT_W;

            uint32_t o00[4], dxx[4], rst[4];
            float w[4][4];
            #pragma unroll
            for (int iy = 0; iy < RATIO; ++iy) {
                float yy = y1 + ((float)(ph * RATIO + iy) + 0.5f) * step_y;
                bool  vy = (yy >= -1.0f) && (yy <= (float)FH);
                float yc = fminf(fmaxf(yy, 0.0f), (float)(FH - 1));
                int   yi0 = (int)yc;
                float ly = yc - (float)yi0, hy = 1.0f - ly;
                uint32_t row0  = (uint32_t)yi0 * (FW * CCH * 2);
                uint32_t rstep = (yi0 < FH - 1) ? (FW * CCH * 2) : 0u;
                #pragma unroll
                for (int ix = 0; ix < RATIO; ++ix) {
                    int s = iy * RATIO + ix;
                    float xx = x1 + ((float)(pw * RATIO + ix) + 0.5f) * step_x;
                    bool  vx = (xx >= -1.0f) && (xx <= (float)FW);
                    float xc = fminf(fmaxf(xx, 0.0f), (float)(FW - 1));
                    int   xi0 = (int)xc;
                    float lx = xc - (float)xi0, hx = 1.0f - lx;
                    float vm  = (vy && vx) ? 0.25f : 0.0f;
                    float hyv = hy * vm, lyv = ly * vm;
                    o00[s] = row0 + (uint32_t)xi0 * (CCH * 2) + laneoff;
                    dxx[s] = (xi0 < FW - 1) ? (CCH * 2) : 0u;
                    rst[s] = rstep;
                    w[s][0] = hyv * hx; w[s][1] = hyv * lx;
                    w[s][2] = lyv * hx; w[s][3] = lyv * lx;
                }
            }

            H8 v[16];
            #pragma unroll
            for (int s = 0; s < 4; ++s) {
                v[4*s+0] = *(const H8*)(base + o00[s]);
                v[4*s+1] = *(const H8*)(base + o00[s] + dxx[s]);
                v[4*s+2] = *(const H8*)(base + o00[s] + rst[s]);
                v[4*s+3] = *(const H8*)(base + o00[s] + rst[s] + dxx[s]);
            }
            // Loads (memory reads) cannot sink past a memory-clobber asm:
            // forces all 16 loads in flight before any consumption.
            __asm__ volatile("" ::: "memory");

            float acc[8];
            #pragma unroll
            for (int k = 0; k < 8; ++k) acc[k] = 0.0f;
            #pragma unroll
            for (int s = 0; s < 4; ++s) {
                #pragma unroll
                for (int c4 = 0; c4 < 4; ++c4)
                    acc8(acc, v[4*s+c4], w[s][c4]);
            }

            // Scalar LDS writes: bank = (p + 8l + k) & 31 -> 64 lanes hit 64
            // distinct (mod 32 -> 2/bank = free) banks. Zero conflicts.
            float* lp = &lds[p * LROW + l * 8];
            #pragma unroll
            for (int k = 0; k < 8; ++k) lp[k] = acc[k];
        }
    }
    __syncthreads();

    // Contiguous 64*49-float region of (N,C,7,7); write-once -> nontemporal.
    // Read bank stride 1 (LROW odd) -> conflict-free.
    float* oblk = out + ((size_t)n * CCH + cq * 64) * NPOS;
    #pragma unroll 1
    for (int o = tid; o < 64 * NPOS; o += 256) {
        int c = o / NPOS;          // magic-mul
        int p = o - c * NPOS;
        __builtin_nontemporal_store(lds[p * LROW + c], &oblk[o]);
    }
}

// ---------------- Fallback: direct NCHW (round-1 kernel) --------------------
__global__ __launch_bounds__(256) void roi_align_kernel(
    const float* __restrict__ feat, const float* __restrict__ rois,
    float* __restrict__ out, int N, int C, int H, int W)
{
    int idx = blockIdx.x * blockDim.x + threadIdx.x;
    int total = N * C * OUT_H * OUT_W;
    if (idx >= total) return;
    int pw = idx % OUT_W;
    int ph = (idx / OUT_W) % OUT_H;
    int c  = (idx / (OUT_W * OUT_H)) % C;
    int n  = idx / (OUT_W * OUT_H * C);
    const float* r = rois + (size_t)n * 5;
    int   b  = (int)r[0];
    float x1 = r[1] * SCALE, y1 = r[2] * SCALE;
    float roi_w = fmaxf(r[3] * SCALE - x1, 1.0f);
    float roi_h = fmaxf(r[4] * SCALE - y1, 1.0f);
    float step_y = roi_h * (1.0f / (OUT_H * RATIO));
    float step_x = roi_w * (1.0f / (OUT_W * RATIO));
    const float* fptr = feat + ((size_t)b * C + c) * (size_t)(H * W);
    float acc = 0.0f;
    #pragma unroll
    for (int iy = 0; iy < RATIO; ++iy) {
        float y = y1 + ((float)(ph * RATIO + iy) + 0.5f) * step_y;
        bool vy = (y >= -1.0f) && (y <= (float)H);
        float ycl = fminf(fmaxf(y, 0.0f), (float)(H - 1));
        int y0 = (int)floorf(ycl), y1i = min(y0 + 1, H - 1);
        float ly = ycl - (float)y0, hy = 1.0f - ly;
        #pragma unroll
        for (int ix = 0; ix < RATIO; ++ix) {
            float x = x1 + ((float)(pw * RATIO + ix) + 0.5f) * step_x;
            bool vx = (x >= -1.0f) && (x <= (float)W);
            float xcl = fminf(fmaxf(x, 0.0f), (float)(W - 1));
            int x0 = (int)floorf(xcl), x1i = min(x0 + 1, W - 1);
            float lx = xcl - (float)x0, hx = 1.0f - lx;
            const float* row0 = fptr + (size_t)y0 * W;
            const float* row1 = fptr + (size_t)y1i * W;
            float v = hy * hx * row0[x0] + hy * lx * row0[x1i]
                    + ly * hx * row1[x0] + ly * lx * row1[x1i];
            acc += (vy && vx) ? v : 0.0f;
        }
    }
    out[idx] = acc * (1.0f / (RATIO * RATIO));
}

extern "C" void kernel_launch(void* const* d_in, const int* in_sizes, int n_in,
                              void* d_out, int out_size, void* d_ws, size_t ws_size,
                              hipStream_t stream) {
    const float* feat = (const float*)d_in[0];
    const float* rois = (const float*)d_in[1];
    float* out = (float*)d_out;

    const int N = in_sizes[1] / 5;
    const int B = in_sizes[0] / (CCH * FHW);

    size_t need = (size_t)B * FHW * CCH * sizeof(__half);
    if (ws_size >= need) {
        __half* featT = (__half*)d_ws;
        transpose_cp<<<B * 4 * 625, 256, 0, stream>>>(feat, featT);
        roi_gather_v8<<<4 * N, 256, 0, stream>>>(featT, rois, out, N);
    } else {
        int total = N * CCH * OUT_H * OUT_W;
        roi_align_kernel<<<(total + 255) / 256, 256, 0, stream>>>(
            feat, rois, out, N, CCH, FH, FW);
    }
}

// Round 11
// 60.293 us; speedup vs baseline: 1.0359x; 1.0359x over previous
//
#include <hip/hip_runtime.h>
#include <hip/hip_fp16.h>

#define OUT_H 7
#define OUT_W 7
#define NPOS  49
#define RATIO 2
#define SCALE 0.25f
#define CCH 256
#define FH 200
#define FW 200
#define FHW (FH * FW)          // 40000
#define LROW 65                // ODD row stride (floats): bank stride 1 -> conflict-free

struct __align__(16) H8 { __half2 h[4]; };   // 8 fp16 channels

__device__ __forceinline__ void acc8(float (&a)[8], const H8& v, float w) {
    #pragma unroll
    for (int k = 0; k < 4; ++k) {
        a[2*k]   = fmaf(__low2float(v.h[k]),  w, a[2*k]);
        a[2*k+1] = fmaf(__high2float(v.h[k]), w, a[2*k+1]);
    }
}

// ---------------- Transpose: (B, 256, 40000) fp32 -> (B, 40000, 256) fp16 ---
// Proven ~15 us (HBM/L3-bound). Do not touch.
__global__ __launch_bounds__(256) void transpose_cp(
    const float* __restrict__ in, __half* __restrict__ outT)
{
    int bid = blockIdx.x;               // grid = B * 4 * 625
    int pt   = bid % 625;               // pixel tile (64 pixels)
    int rest = bid / 625;
    int ct   = rest & 3;                // channel tile (64 ch)
    int b    = rest >> 2;

    __shared__ unsigned short tile[64][66];   // [pix][c]
    int tid = threadIdx.x;
    int pix0 = pt * 64, c0 = ct * 64;
    int xl = tid & 63;

    const float* src = in + ((size_t)b * CCH + c0) * FHW + pix0;
    #pragma unroll
    for (int k = 0; k < 16; ++k) {
        int cl = (tid >> 6) + 4 * k;    // 0..63
        tile[xl][cl] = __half_as_ushort(__float2half(src[(size_t)cl * FHW + xl]));
    }
    __syncthreads();

    __half* dst = outT + ((size_t)b * FHW + pix0) * CCH + c0;
    #pragma unroll
    for (int j = 0; j < 8; ++j) {
        int idx = tid + 256 * j;        // 0..2047
        int pl = idx >> 5;              // 0..63
        int cp = idx & 31;              // half2 index: c = 2*cp
        *(unsigned int*)((char*)dst + (size_t)pl * (CCH * 2) + 4 * cp) =
            *(const unsigned int*)&tile[pl][2 * cp];
    }
}

// ---------------- ROI Align gather v9: sched_barrier-pinned 16-deep MLP -----
// grid = 4N: block (n = bid>>2, cq = bid&3) owns 64 channels of ROI n.
// Per position: compute all corner addrs/weights, issue ALL 16 H8 loads, then
// __builtin_amdgcn_sched_barrier(0) — NOTHING crosses it, so the compiler
// cannot interleave FMAs into the load cluster (that's what silently killed
// v7/v8: reg-only FMAs hoist past "memory" clobbers, VGPR stayed 44).
// Forces 64 live data VGPRs => 16 outstanding VMEM loads per thread.
// __launch_bounds__(256,4): VGPR cap 128, 16 waves/CU.
__global__ __launch_bounds__(256, 4) void roi_gather_v9(
    const __half* __restrict__ featT,  // (B, 40000, 256) fp16
    const float* __restrict__ rois,    // (N, 5)
    float* __restrict__ out,           // (N, 256, 7, 7)
    int N)
{
    int bid = blockIdx.x;
    int n  = bid >> 2;
    int cq = bid & 3;
    int tid = threadIdx.x;
    int wave = tid >> 6, lane = tid & 63;
    int g = lane >> 3;                  // position group 0..7
    int l = lane & 7;                   // channel group (8 ch)

    __shared__ float lds[NPOS * LROW];

    const float* r = rois + (size_t)n * 5;
    int   b  = (int)r[0];
    float x1 = r[1] * SCALE, y1 = r[2] * SCALE;
    float roi_w = fmaxf(r[3] * SCALE - x1, 1.0f);
    float roi_h = fmaxf(r[4] * SCALE - y1, 1.0f);
    float step_x = roi_w * (1.0f / (OUT_W * RATIO));
    float step_y = roi_h * (1.0f / (OUT_H * RATIO));

    const char* base = (const char*)featT + (size_t)b * ((size_t)FHW * CCH * 2);
    const uint32_t laneoff = (uint32_t)(cq * 64 + l * 8) * 2;

    #pragma unroll 1
    for (int rnd = 0; rnd < 2; ++rnd) {
        int p = rnd * 32 + wave * 8 + g;    // 0..63
        if (p < NPOS) {
            int ph = p / OUT_W;
            int pw = p - ph * OUT_W;

            uint32_t o00[4], dxx[4], rst[4];
            float w[4][4];
            #pragma unroll
            for (int iy = 0; iy < RATIO; ++iy) {
                float yy = y1 + ((float)(ph * RATIO + iy) + 0.5f) * step_y;
                bool  vy = (yy >= -1.0f) && (yy <= (float)FH);
                float yc = fminf(fmaxf(yy, 0.0f), (float)(FH - 1));
                int   yi0 = (int)yc;
                float ly = yc - (float)yi0, hy = 1.0f - ly;
                uint32_t row0  = (uint32_t)yi0 * (FW * CCH * 2);
                uint32_t rstep = (yi0 < FH - 1) ? (FW * CCH * 2) : 0u;
                #pragma unroll
                for (int ix = 0; ix < RATIO; ++ix) {
                    int s = iy * RATIO + ix;
                    float xx = x1 + ((float)(pw * RATIO + ix) + 0.5f) * step_x;
                    bool  vx = (xx >= -1.0f) && (xx <= (float)FW);
                    float xc = fminf(fmaxf(xx, 0.0f), (float)(FW - 1));
                    int   xi0 = (int)xc;
                    float lx = xc - (float)xi0, hx = 1.0f - lx;
                    float vm  = (vy && vx) ? 0.25f : 0.0f;
                    float hyv = hy * vm, lyv = ly * vm;
                    o00[s] = row0 + (uint32_t)xi0 * (CCH * 2) + laneoff;
                    dxx[s] = (xi0 < FW - 1) ? (CCH * 2) : 0u;
                    rst[s] = rstep;
                    w[s][0] = hyv * hx; w[s][1] = hyv * lx;
                    w[s][2] = lyv * hx; w[s][3] = lyv * lx;
                }
            }

            H8 v[16];
            #pragma unroll
            for (int s = 0; s < 4; ++s) {
                v[4*s+0] = *(const H8*)(base + o00[s]);
                v[4*s+1] = *(const H8*)(base + o00[s] + dxx[s]);
                v[4*s+2] = *(const H8*)(base + o00[s] + rst[s]);
                v[4*s+3] = *(const H8*)(base + o00[s] + rst[s] + dxx[s]);
            }
            // Hard scheduling fence: no instruction may cross. All 16 loads
            // issue before any FMA -> 16 outstanding VMEM per thread.
            __builtin_amdgcn_sched_barrier(0);

            float acc[8];
            #pragma unroll
            for (int k = 0; k < 8; ++k) acc[k] = 0.0f;
            #pragma unroll
            for (int s = 0; s < 4; ++s) {
                #pragma unroll
                for (int c4 = 0; c4 < 4; ++c4)
                    acc8(acc, v[4*s+c4], w[s][c4]);
            }

            // Scalar LDS writes: bank = (p + 8l + k) & 31 -> 2/bank = free.
            float* lp = &lds[p * LROW + l * 8];
            #pragma unroll
            for (int k = 0; k < 8; ++k) lp[k] = acc[k];
        }
    }
    __syncthreads();

    // Contiguous 64*49-float region of (N,C,7,7); write-once -> nontemporal.
    // Read bank stride 1 (LROW odd) -> conflict-free.
    float* oblk = out + ((size_t)n * CCH + cq * 64) * NPOS;
    #pragma unroll 1
    for (int o = tid; o < 64 * NPOS; o += 256) {
        int c = o / NPOS;          // magic-mul
        int p = o - c * NPOS;
        __builtin_nontemporal_store(lds[p * LROW + c], &oblk[o]);
    }
}

// ---------------- Fallback: direct NCHW (round-1 kernel) --------------------
__global__ __launch_bounds__(256) void roi_align_kernel(
    const float* __restrict__ feat, const float* __restrict__ rois,
    float* __restrict__ out, int N, int C, int H, int W)
{
    int idx = blockIdx.x * blockDim.x + threadIdx.x;
    int total = N * C * OUT_H * OUT_W;
    if (idx >= total) return;
    int pw = idx % OUT_W;
    int ph = (idx / OUT_W) % OUT_H;
    int c  = (idx / (OUT_W * OUT_H)) % C;
    int n  = idx / (OUT_W * OUT_H * C);
    const float* r = rois + (size_t)n * 5;
    int   b  = (int)r[0];
    float x1 = r[1] * SCALE, y1 = r[2] * SCALE;
    float roi_w = fmaxf(r[3] * SCALE - x1, 1.0f);
    float roi_h = fmaxf(r[4] * SCALE - y1, 1.0f);
    float step_y = roi_h * (1.0f / (OUT_H * RATIO));
    float step_x = roi_w * (1.0f / (OUT_W * RATIO));
    const float* fptr = feat + ((size_t)b * C + c) * (size_t)(H * W);
    float acc = 0.0f;
    #pragma unroll
    for (int iy = 0; iy < RATIO; ++iy) {
        float y = y1 + ((float)(ph * RATIO + iy) + 0.5f) * step_y;
        bool vy = (y >= -1.0f) && (y <= (float)H);
        float ycl = fminf(fmaxf(y, 0.0f), (float)(H - 1));
        int y0 = (int)floorf(ycl), y1i = min(y0 + 1, H - 1);
        float ly = ycl - (float)y0, hy = 1.0f - ly;
        #pragma unroll
        for (int ix = 0; ix < RATIO; ++ix) {
            float x = x1 + ((float)(pw * RATIO + ix) + 0.5f) * step_x;
            bool vx = (x >= -1.0f) && (x <= (float)W);
            float xcl = fminf(fmaxf(x, 0.0f), (float)(W - 1));
            int x0 = (int)floorf(xcl), x1i = min(x0 + 1, W - 1);
            float lx = xcl - (float)x0, hx = 1.0f - lx;
            const float* row0 = fptr + (size_t)y0 * W;
            const float* row1 = fptr + (size_t)y1i * W;
            float v = hy * hx * row0[x0] + hy * lx * row0[x1i]
                    + ly * hx * row1[x0] + ly * lx * row1[x1i];
            acc += (vy && vx) ? v : 0.0f;
        }
    }
    out[idx] = acc * (1.0f / (RATIO * RATIO));
}

extern "C" void kernel_launch(void* const* d_in, const int* in_sizes, int n_in,
                              void* d_out, int out_size, void* d_ws, size_t ws_size,
                              hipStream_t stream) {
    const float* feat = (const float*)d_in[0];
    const float* rois = (const float*)d_in[1];
    float* out = (float*)d_out;

    const int N = in_sizes[1] / 5;
    const int B = in_sizes[0] / (CCH * FHW);

    size_t need = (size_t)B * FHW * CCH * sizeof(__half);
    if (ws_size >= need) {
        __half* featT = (__half*)d_ws;
        transpose_cp<<<B * 4 * 625, 256, 0, stream>>>(feat, featT);
        roi_gather_v9<<<4 * N, 256, 0, stream>>>(featT, rois, out, N);
    } else {
        int total = N * CCH * OUT_H * OUT_W;
        roi_align_kernel<<<(total + 255) / 256, 256, 0, stream>>>(
            feat, rois, out, N, CCH, FH, FW);
    }
}